// Round 9
// baseline (1349.727 us; speedup 1.0000x reference)
//
#include <hip/hip_runtime.h>

// MultiAdapterLinear: out = x @ W^T + b + 2.0 * (B[t] @ (A[t] @ x)) per-row task t
// Strategy: bucket rows by task; pre-gather x into bucket order as bf16;
// fused 128x128 bf16-MFMA GEMM, 256 thr, ~35KB LDS -> 4 WG/CU (cross-WG
// latency hiding), L2-footprint-aware XCD decode, LoRA balanced across all
// 4 waves, axs aliased into xs, B pre-padded to K=32 (epilogue B-frags are
// direct global loads), direct stores.

#define D_IN   1024
#define D_OUTV 1024
#define NTASK  32
#define NROWS  32768
#define RLORA  16
#define SCALE  2.0f

typedef unsigned short u16;
typedef __attribute__((ext_vector_type(4))) unsigned short u16x4;
typedef __attribute__((ext_vector_type(8))) unsigned short u16x8;
typedef __attribute__((ext_vector_type(8))) short s16x8;
typedef __attribute__((ext_vector_type(4))) float f32x4;

// workspace layout (bytes)
#define WB_OFF   (0)
#define AB_OFF   (2*1024*1024)
#define BB_OFF   (3*1024*1024)           // Bbp: 32*1024*32*2B = 2 MB (K padded)
#define CNT_OFF  (5*1024*1024)
#define RIDX_OFF (CNT_OFF + 512)
#define XG_OFF   (8ull*1024*1024)

__device__ __forceinline__ u16 f2bf(float f) {
  union { float f; unsigned u; } v; v.f = f;
  unsigned r = v.u + 0x7fffu + ((v.u >> 16) & 1u);
  return (u16)(r >> 16);
}

__device__ __forceinline__ void gl2lds16(const void* g, void* s) {
  __builtin_amdgcn_global_load_lds(
      (const __attribute__((address_space(1))) unsigned*)g,
      (__attribute__((address_space(3))) unsigned*)s, 16, 0, 0);
}

// W -> Wb (bf16), A -> Ab (bf16), B -> Bbp (bf16, rank padded 16->32 w/ zeros)
__global__ void k_convert(const float* __restrict__ W, const float* __restrict__ A,
                          const float* __restrict__ B, u16* __restrict__ Wb,
                          u16* __restrict__ Ab, u16* __restrict__ Bbp) {
  int g = blockIdx.x * blockDim.x + threadIdx.x;  // group of 4 elems
  const int NW = D_OUTV * D_IN / 4;               // 262144
  const int NA = NTASK * RLORA * D_IN / 4;        // 131072
  const int NB = NTASK * D_OUTV * RLORA / 4;      // 131072
  if (g < NW) {
    f32x4 v = *(const f32x4*)(W + (size_t)g * 4);
    u16x4 o; o[0]=f2bf(v[0]); o[1]=f2bf(v[1]); o[2]=f2bf(v[2]); o[3]=f2bf(v[3]);
    *(u16x4*)(Wb + (size_t)g * 4) = o;
  } else if (g < NW + NA) {
    int idx = g - NW;
    f32x4 v = *(const f32x4*)(A + (size_t)idx * 4);
    u16x4 o; o[0]=f2bf(v[0]); o[1]=f2bf(v[1]); o[2]=f2bf(v[2]); o[3]=f2bf(v[3]);
    *(u16x4*)(Ab + (size_t)idx * 4) = o;
  } else if (g < NW + NA + NB) {
    int idx = g - NW - NA;                        // 4 elems within one 16-row
    f32x4 v = *(const f32x4*)(B + (size_t)idx * 4);
    u16x4 o; o[0]=f2bf(v[0]); o[1]=f2bf(v[1]); o[2]=f2bf(v[2]); o[3]=f2bf(v[3]);
    *(u16x4*)(Bbp + (size_t)(idx >> 2) * 32 + (idx & 3) * 4) = o;
  } else {
    int idx = g - NW - NA - NB;                   // zero the pad half
    u16x4 z = {0, 0, 0, 0};
    *(u16x4*)(Bbp + (size_t)(idx >> 2) * 32 + 16 + (idx & 3) * 4) = z;
  }
}

__global__ void k_hist(const int* __restrict__ tasks, int* __restrict__ cnt) {
  __shared__ int h[NTASK];
  int tid = threadIdx.x;
  if (tid < NTASK) h[tid] = 0;
  __syncthreads();
  atomicAdd(&h[tasks[blockIdx.x * 256 + tid]], 1);
  __syncthreads();
  if (tid < NTASK) atomicAdd(&cnt[tid], h[tid]);
}

__global__ void k_scan(int* __restrict__ cnt) {
  int t = threadIdx.x;
  int c = (t < NTASK) ? cnt[t] : 0;
  int v = c;
  for (int d = 1; d < NTASK; d <<= 1) {
    int u = __shfl_up(v, d, 64);
    if (t >= d) v += u;
  }
  if (t < NTASK) {
    int ex = v - c;
    cnt[64 + t] = ex;
    cnt[32 + t] = ex;
    if (t == NTASK - 1) cnt[64 + NTASK] = v;
  }
}

__global__ void k_scatter(const int* __restrict__ tasks, int* __restrict__ cnt,
                          int* __restrict__ ridx) {
  __shared__ int h[NTASK], basev[NTASK];
  int tid = threadIdx.x;
  int b = blockIdx.x * 256 + tid;
  int t = tasks[b];
  if (tid < NTASK) h[tid] = 0;
  __syncthreads();
  atomicAdd(&h[t], 1);
  __syncthreads();
  if (tid < NTASK) {
    basev[tid] = atomicAdd(&cnt[32 + tid], h[tid]);
    h[tid] = 0;
  }
  __syncthreads();
  int r = atomicAdd(&h[t], 1);
  ridx[basev[t] + r] = b;
}

__global__ void k_gatherx(const float* __restrict__ x, const int* __restrict__ ridx,
                          u16* __restrict__ xg) {
  int g = blockIdx.x * 256 + threadIdx.x;
  int pos = g >> 7;
  int c8  = (g & 127) << 3;
  int src = ridx[pos];
  f32x4 a = *(const f32x4*)(x + (size_t)src * D_IN + c8);
  f32x4 b = *(const f32x4*)(x + (size_t)src * D_IN + c8 + 4);
  u16x8 o;
  o[0] = f2bf(a[0]); o[1] = f2bf(a[1]); o[2] = f2bf(a[2]); o[3] = f2bf(a[3]);
  o[4] = f2bf(b[0]); o[5] = f2bf(b[1]); o[6] = f2bf(b[2]); o[7] = f2bf(b[3]);
  *(u16x8*)(xg + (size_t)pos * D_IN + c8) = o;
}

// ---------------- main fused GEMM ----------------
#define BM 128
#define BN 128
#define BK 64
#define NTHR 256
#define SLOTS 4
#define NWG (8 * NTASK * SLOTS)   // 1024 WGs = 4 per CU

__global__ __launch_bounds__(NTHR, 4) void k_main_c(
    const u16* __restrict__ xg, const float* __restrict__ bias,
    const u16* __restrict__ Wb, const u16* __restrict__ Ab, const u16* __restrict__ Bbp,
    const int* __restrict__ cnt, const int* __restrict__ ridx,
    float* __restrict__ out) {
  __shared__ __align__(16) u16 xs[BM * BK];    // 16 KB (axs aliases first 8 KB)
  __shared__ __align__(16) u16 wls[BN * BK];   // 16 KB
  __shared__ u16 als[RLORA * BK];              // 2 KB
  __shared__ int rowid_l[BM];                  // 0.5 KB  -> ~34.5 KB total
  u16* axs = xs;                               // ax tile (rank padded 16->32)

  const int tid = threadIdx.x;
  const int l   = tid & 63;
  const int w   = tid >> 6;          // 0..3
  const int wr  = w >> 1;            // 0..1 : 64-row slice
  const int wc  = w & 1;             // 0..1 : 64-col slice
  const int l15 = l & 15;
  const int lg  = l >> 4;

  // L2-footprint-aware decode: flat&7 = XCD; cb innermost so the 8 adjacent
  // WGs on an XCD share one 256KB xg chunk and cover the whole 2MB W.
  const int flat = blockIdx.x;
  const int xcd  = flat & 7;
  const int j    = flat >> 3;                 // 0..127
  const int cb   = j & 7;                     // colblock 0..7 (inner)
  const int g    = j >> 3;                    // 0..15
  const int task = xcd + 8 * (g & 3);
  const int slot = g >> 2;                    // 0..3

  const int o0    = cnt[64 + task];
  const int count = cnt[64 + task + 1] - o0;

  for (int chunk = slot; chunk * BM < count; chunk += SLOTS) {
    const int base = chunk * BM;
    __syncthreads();  // protect rowid_l / xs(axs) from previous chunk readers
    if (tid < BM) {
      int s = base + tid;
      rowid_l[tid] = (s < count) ? ridx[o0 + s] : 0;
    }

    f32x4 acc[4][4];
    f32x4 axc[2];
    const f32x4 z4 = {0.f, 0.f, 0.f, 0.f};
    axc[0] = z4; axc[1] = z4;
#pragma unroll
    for (int m = 0; m < 4; m++)
#pragma unroll
      for (int n = 0; n < 4; n++) acc[m][n] = z4;

    for (int kk = 0; kk < D_IN; kk += BK) {
      __syncthreads();  // previous compute done before overwriting tiles
      // x tile: contiguous bucketed bf16 rows; source chunk pre-swizzled
#pragma unroll
      for (int i = 0; i < 4; i++) {
        int ch = i * NTHR + tid;          // 0..1023
        int r = ch >> 3, c = ch & 7;
        int gr = o0 + base + r;
        if (gr > NROWS - 1) gr = NROWS - 1;   // tail clamp (masked at store)
        gl2lds16(xg + (size_t)gr * D_IN + kk + ((c ^ (r & 7)) << 3), &xs[ch * 8]);
      }
      // W tile
#pragma unroll
      for (int i = 0; i < 4; i++) {
        int ch = i * NTHR + tid;
        int wrow = ch >> 3, c = ch & 7;
        gl2lds16(Wb + (size_t)(cb * BN + wrow) * D_IN + kk + ((c ^ (wrow & 7)) << 3),
                 &wls[ch * 8]);
      }
      // A[t] tile
      if (tid < 128) {
        int r = tid >> 3, c = tid & 7;
        gl2lds16(Ab + (size_t)(task * RLORA + r) * D_IN + kk + ((c ^ (r & 7)) << 3),
                 &als[tid * 8]);
      }
      __syncthreads();  // drains vmcnt (global_load_lds) + lgkm

#pragma unroll
      for (int k0 = 0; k0 < BK; k0 += 32) {
        int kf = k0 + lg * 8;
        s16x8 xf[4], wf[4];
#pragma unroll
        for (int m = 0; m < 4; m++) {
          int row = wr * 64 + m * 16 + l15;
          xf[m] = *(const s16x8*)&xs[row * BK + (kf ^ ((row & 7) << 3))];
        }
#pragma unroll
        for (int n = 0; n < 4; n++) {
          int col = wc * 64 + n * 16 + l15;
          wf[n] = *(const s16x8*)&wls[col * BK + (kf ^ ((col & 7) << 3))];
        }
#pragma unroll
        for (int m = 0; m < 4; m++)
#pragma unroll
          for (int n = 0; n < 4; n++)
            acc[m][n] = __builtin_amdgcn_mfma_f32_16x16x32_bf16(xf[m], wf[n], acc[m][n], 0, 0, 0);
        // LoRA down-proj, balanced: wave (wr,wc) owns m-frags {wc*2, wc*2+1}
        {
          s16x8 af = *(const s16x8*)&als[l15 * BK + (kf ^ ((l15 & 7) << 3))];
#pragma unroll
          for (int i = 0; i < 2; i++)
            axc[i] = __builtin_amdgcn_mfma_f32_16x16x32_bf16(xf[wc * 2 + i], af, axc[i], 0, 0, 0);
        }
      }
    }
    __syncthreads();  // all compute done; xs dead -> axs may overwrite

    // write scaled ax to LDS (bf16, swizzled) + explicit zero pad complement
#pragma unroll
    for (int i = 0; i < 2; i++) {
#pragma unroll
      for (int j2 = 0; j2 < 4; j2++) {
        int row = wr * 64 + (wc * 2 + i) * 16 + lg * 4 + j2;
        int swz = (row & 3) << 3;
        axs[row * 32 + (l15 ^ swz)] = f2bf(axc[i][j2] * SCALE);
        axs[row * 32 + ((l15 + 16) ^ swz)] = 0;
      }
    }
    __syncthreads();

    // lora up-proj: one K=32 MFMA per fragment (B pre-padded), + bias, store
    int kf2 = lg * 8;
    s16x8 blf[4];
#pragma unroll
    for (int n = 0; n < 4; n++) {   // direct global B-frags (L2-hit)
      int colg = cb * BN + wc * 64 + n * 16 + l15;
      blf[n] = *(const s16x8*)(Bbp + ((size_t)(task * D_OUTV) + colg) * 32 + kf2);
    }
    s16x8 axf[4];
#pragma unroll
    for (int m = 0; m < 4; m++) {
      int row = wr * 64 + m * 16 + l15;
      axf[m] = *(const s16x8*)&axs[row * 32 + (kf2 ^ ((row & 3) << 3))];
    }
#pragma unroll
    for (int n = 0; n < 4; n++) {
      int colg = cb * BN + wc * 64 + n * 16 + l15;
      float bv = bias[colg];
#pragma unroll
      for (int m = 0; m < 4; m++) {
        f32x4 r = __builtin_amdgcn_mfma_f32_16x16x32_bf16(axf[m], blf[n], acc[m][n], 0, 0, 0);
#pragma unroll
        for (int j2 = 0; j2 < 4; j2++) {
          int lrow = wr * 64 + m * 16 + lg * 4 + j2;
          if (base + lrow < count) {
            int grow = rowid_l[lrow];
            out[(size_t)grow * D_OUTV + colg] = r[j2] + bv;
          }
        }
      }
    }
  }
}

extern "C" void kernel_launch(void* const* d_in, const int* in_sizes, int n_in,
                              void* d_out, int out_size, void* d_ws, size_t ws_size,
                              hipStream_t stream) {
  const float* x     = (const float*)d_in[0];
  const int*   tasks = (const int*)d_in[1];
  const float* W     = (const float*)d_in[2];
  const float* bias  = (const float*)d_in[3];
  const float* A     = (const float*)d_in[4];
  const float* B     = (const float*)d_in[5];
  float* out = (float*)d_out;
  char* ws = (char*)d_ws;
  u16* Wb  = (u16*)(ws + WB_OFF);
  u16* Ab  = (u16*)(ws + AB_OFF);
  u16* Bbp = (u16*)(ws + BB_OFF);
  int* cnt  = (int*)(ws + CNT_OFF);
  int* ridx = (int*)(ws + RIDX_OFF);
  u16* xg   = (u16*)(ws + XG_OFF);

  hipMemsetAsync(cnt, 0, 512, stream);
  k_convert<<<2560, 256, 0, stream>>>(W, A, B, Wb, Ab, Bbp);
  k_hist<<<NROWS / 256, 256, 0, stream>>>(tasks, cnt);
  k_scan<<<1, 64, 0, stream>>>(cnt);
  k_scatter<<<NROWS / 256, 256, 0, stream>>>(tasks, cnt, ridx);
  k_gatherx<<<NROWS * D_IN / 8 / 256, 256, 0, stream>>>(x, ridx, xg);
  k_main_c<<<NWG, NTHR, 0, stream>>>(xg, bias, Wb, Ab, Bbp, cnt, ridx, out);
}

// Round 10
// 235.553 us; speedup vs baseline: 5.7300x; 5.7300x over previous
//
#include <hip/hip_runtime.h>

// MultiAdapterLinear: out = x @ W^T + b + 2.0 * (B[t] @ (A[t] @ x)) per-row task t
// Strategy: bucket rows by task; pre-gather x into bucket order as bf16;
// fused 128x128 bf16-MFMA GEMM, 256 thr, ~35KB LDS -> 4 WG/CU (cross-WG
// latency hiding), L2-footprint-aware XCD decode, LoRA balanced across all
// 4 waves via WAVE-UNIFORM BRANCH with compile-time fragment indices
// (rule #20: runtime-indexed reg arrays spill to scratch -- R9 bug),
// axs aliased into xs, B pre-padded to K=32, direct stores.

#define D_IN   1024
#define D_OUTV 1024
#define NTASK  32
#define NROWS  32768
#define RLORA  16
#define SCALE  2.0f

typedef unsigned short u16;
typedef __attribute__((ext_vector_type(4))) unsigned short u16x4;
typedef __attribute__((ext_vector_type(8))) unsigned short u16x8;
typedef __attribute__((ext_vector_type(8))) short s16x8;
typedef __attribute__((ext_vector_type(4))) float f32x4;

// workspace layout (bytes)
#define WB_OFF   (0)
#define AB_OFF   (2*1024*1024)
#define BB_OFF   (3*1024*1024)           // Bbp: 32*1024*32*2B = 2 MB (K padded)
#define CNT_OFF  (5*1024*1024)
#define RIDX_OFF (CNT_OFF + 512)
#define XG_OFF   (8ull*1024*1024)

__device__ __forceinline__ u16 f2bf(float f) {
  union { float f; unsigned u; } v; v.f = f;
  unsigned r = v.u + 0x7fffu + ((v.u >> 16) & 1u);
  return (u16)(r >> 16);
}

__device__ __forceinline__ void gl2lds16(const void* g, void* s) {
  __builtin_amdgcn_global_load_lds(
      (const __attribute__((address_space(1))) unsigned*)g,
      (__attribute__((address_space(3))) unsigned*)s, 16, 0, 0);
}

// W -> Wb (bf16), A -> Ab (bf16), B -> Bbp (bf16, rank padded 16->32 w/ zeros)
__global__ void k_convert(const float* __restrict__ W, const float* __restrict__ A,
                          const float* __restrict__ B, u16* __restrict__ Wb,
                          u16* __restrict__ Ab, u16* __restrict__ Bbp) {
  int g = blockIdx.x * blockDim.x + threadIdx.x;  // group of 4 elems
  const int NW = D_OUTV * D_IN / 4;               // 262144
  const int NA = NTASK * RLORA * D_IN / 4;        // 131072
  const int NB = NTASK * D_OUTV * RLORA / 4;      // 131072
  if (g < NW) {
    f32x4 v = *(const f32x4*)(W + (size_t)g * 4);
    u16x4 o; o[0]=f2bf(v[0]); o[1]=f2bf(v[1]); o[2]=f2bf(v[2]); o[3]=f2bf(v[3]);
    *(u16x4*)(Wb + (size_t)g * 4) = o;
  } else if (g < NW + NA) {
    int idx = g - NW;
    f32x4 v = *(const f32x4*)(A + (size_t)idx * 4);
    u16x4 o; o[0]=f2bf(v[0]); o[1]=f2bf(v[1]); o[2]=f2bf(v[2]); o[3]=f2bf(v[3]);
    *(u16x4*)(Ab + (size_t)idx * 4) = o;
  } else if (g < NW + NA + NB) {
    int idx = g - NW - NA;                        // 4 elems within one 16-row
    f32x4 v = *(const f32x4*)(B + (size_t)idx * 4);
    u16x4 o; o[0]=f2bf(v[0]); o[1]=f2bf(v[1]); o[2]=f2bf(v[2]); o[3]=f2bf(v[3]);
    *(u16x4*)(Bbp + (size_t)(idx >> 2) * 32 + (idx & 3) * 4) = o;
  } else {
    int idx = g - NW - NA - NB;                   // zero the pad half
    u16x4 z = {0, 0, 0, 0};
    *(u16x4*)(Bbp + (size_t)(idx >> 2) * 32 + 16 + (idx & 3) * 4) = z;
  }
}

__global__ void k_hist(const int* __restrict__ tasks, int* __restrict__ cnt) {
  __shared__ int h[NTASK];
  int tid = threadIdx.x;
  if (tid < NTASK) h[tid] = 0;
  __syncthreads();
  atomicAdd(&h[tasks[blockIdx.x * 256 + tid]], 1);
  __syncthreads();
  if (tid < NTASK) atomicAdd(&cnt[tid], h[tid]);
}

__global__ void k_scan(int* __restrict__ cnt) {
  int t = threadIdx.x;
  int c = (t < NTASK) ? cnt[t] : 0;
  int v = c;
  for (int d = 1; d < NTASK; d <<= 1) {
    int u = __shfl_up(v, d, 64);
    if (t >= d) v += u;
  }
  if (t < NTASK) {
    int ex = v - c;
    cnt[64 + t] = ex;
    cnt[32 + t] = ex;
    if (t == NTASK - 1) cnt[64 + NTASK] = v;
  }
}

__global__ void k_scatter(const int* __restrict__ tasks, int* __restrict__ cnt,
                          int* __restrict__ ridx) {
  __shared__ int h[NTASK], basev[NTASK];
  int tid = threadIdx.x;
  int b = blockIdx.x * 256 + tid;
  int t = tasks[b];
  if (tid < NTASK) h[tid] = 0;
  __syncthreads();
  atomicAdd(&h[t], 1);
  __syncthreads();
  if (tid < NTASK) {
    basev[tid] = atomicAdd(&cnt[32 + tid], h[tid]);
    h[tid] = 0;
  }
  __syncthreads();
  int r = atomicAdd(&h[t], 1);
  ridx[basev[t] + r] = b;
}

__global__ void k_gatherx(const float* __restrict__ x, const int* __restrict__ ridx,
                          u16* __restrict__ xg) {
  int g = blockIdx.x * 256 + threadIdx.x;
  int pos = g >> 7;
  int c8  = (g & 127) << 3;
  int src = ridx[pos];
  f32x4 a = *(const f32x4*)(x + (size_t)src * D_IN + c8);
  f32x4 b = *(const f32x4*)(x + (size_t)src * D_IN + c8 + 4);
  u16x8 o;
  o[0] = f2bf(a[0]); o[1] = f2bf(a[1]); o[2] = f2bf(a[2]); o[3] = f2bf(a[3]);
  o[4] = f2bf(b[0]); o[5] = f2bf(b[1]); o[6] = f2bf(b[2]); o[7] = f2bf(b[3]);
  *(u16x8*)(xg + (size_t)pos * D_IN + c8) = o;
}

// ---------------- main fused GEMM ----------------
#define BM 128
#define BN 128
#define BK 64
#define NTHR 256
#define SLOTS 4
#define NWG (8 * NTASK * SLOTS)   // 1024 WGs = 4 per CU

__global__ __launch_bounds__(NTHR, 4) void k_main_c(
    const u16* __restrict__ xg, const float* __restrict__ bias,
    const u16* __restrict__ Wb, const u16* __restrict__ Ab, const u16* __restrict__ Bbp,
    const int* __restrict__ cnt, const int* __restrict__ ridx,
    float* __restrict__ out) {
  __shared__ __align__(16) u16 xs[BM * BK];    // 16 KB (axs aliases first 8 KB)
  __shared__ __align__(16) u16 wls[BN * BK];   // 16 KB
  __shared__ u16 als[RLORA * BK];              // 2 KB
  __shared__ int rowid_l[BM];                  // 0.5 KB  -> ~34.5 KB total
  u16* axs = xs;                               // ax tile (rank padded 16->32)

  const int tid = threadIdx.x;
  const int l   = tid & 63;
  const int w   = tid >> 6;          // 0..3
  const int wr  = w >> 1;            // 0..1 : 64-row slice
  const int wc  = w & 1;             // 0..1 : 64-col slice
  const int l15 = l & 15;
  const int lg  = l >> 4;

  // L2-footprint-aware decode: flat&7 = XCD; cb innermost so the 8 adjacent
  // WGs on an XCD share one 256KB xg chunk and cover the whole 2MB W.
  const int flat = blockIdx.x;
  const int xcd  = flat & 7;
  const int j    = flat >> 3;                 // 0..127
  const int cb   = j & 7;                     // colblock 0..7 (inner)
  const int g    = j >> 3;                    // 0..15
  const int task = xcd + 8 * (g & 3);
  const int slot = g >> 2;                    // 0..3

  const int o0    = cnt[64 + task];
  const int count = cnt[64 + task + 1] - o0;

  for (int chunk = slot; chunk * BM < count; chunk += SLOTS) {
    const int base = chunk * BM;
    __syncthreads();  // protect rowid_l / xs(axs) from previous chunk readers
    if (tid < BM) {
      int s = base + tid;
      rowid_l[tid] = (s < count) ? ridx[o0 + s] : 0;
    }

    f32x4 acc[4][4];
    f32x4 axc[2];
    const f32x4 z4 = {0.f, 0.f, 0.f, 0.f};
    axc[0] = z4; axc[1] = z4;
#pragma unroll
    for (int m = 0; m < 4; m++)
#pragma unroll
      for (int n = 0; n < 4; n++) acc[m][n] = z4;

    for (int kk = 0; kk < D_IN; kk += BK) {
      __syncthreads();  // previous compute done before overwriting tiles
      // x tile: contiguous bucketed bf16 rows; source chunk pre-swizzled
#pragma unroll
      for (int i = 0; i < 4; i++) {
        int ch = i * NTHR + tid;          // 0..1023
        int r = ch >> 3, c = ch & 7;
        int gr = o0 + base + r;
        if (gr > NROWS - 1) gr = NROWS - 1;   // tail clamp (masked at store)
        gl2lds16(xg + (size_t)gr * D_IN + kk + ((c ^ (r & 7)) << 3), &xs[ch * 8]);
      }
      // W tile
#pragma unroll
      for (int i = 0; i < 4; i++) {
        int ch = i * NTHR + tid;
        int wrow = ch >> 3, c = ch & 7;
        gl2lds16(Wb + (size_t)(cb * BN + wrow) * D_IN + kk + ((c ^ (wrow & 7)) << 3),
                 &wls[ch * 8]);
      }
      // A[t] tile
      if (tid < 128) {
        int r = tid >> 3, c = tid & 7;
        gl2lds16(Ab + (size_t)(task * RLORA + r) * D_IN + kk + ((c ^ (r & 7)) << 3),
                 &als[tid * 8]);
      }
      __syncthreads();  // drains vmcnt (global_load_lds) + lgkm

#pragma unroll
      for (int k0 = 0; k0 < BK; k0 += 32) {
        int kf = k0 + lg * 8;
        s16x8 xf[4], wf[4];
#pragma unroll
        for (int m = 0; m < 4; m++) {
          int row = wr * 64 + m * 16 + l15;
          xf[m] = *(const s16x8*)&xs[row * BK + (kf ^ ((row & 7) << 3))];
        }
#pragma unroll
        for (int n = 0; n < 4; n++) {
          int col = wc * 64 + n * 16 + l15;
          wf[n] = *(const s16x8*)&wls[col * BK + (kf ^ ((col & 7) << 3))];
        }
#pragma unroll
        for (int m = 0; m < 4; m++)
#pragma unroll
          for (int n = 0; n < 4; n++)
            acc[m][n] = __builtin_amdgcn_mfma_f32_16x16x32_bf16(xf[m], wf[n], acc[m][n], 0, 0, 0);
        // LoRA down-proj, balanced: wave-uniform branch, COMPILE-TIME indices
        // (rule #20: xf[wc*2+i] runtime index sent xf to scratch in R9)
        {
          s16x8 af = *(const s16x8*)&als[l15 * BK + (kf ^ ((l15 & 7) << 3))];
          if (wc == 0) {
            axc[0] = __builtin_amdgcn_mfma_f32_16x16x32_bf16(xf[0], af, axc[0], 0, 0, 0);
            axc[1] = __builtin_amdgcn_mfma_f32_16x16x32_bf16(xf[1], af, axc[1], 0, 0, 0);
          } else {
            axc[0] = __builtin_amdgcn_mfma_f32_16x16x32_bf16(xf[2], af, axc[0], 0, 0, 0);
            axc[1] = __builtin_amdgcn_mfma_f32_16x16x32_bf16(xf[3], af, axc[1], 0, 0, 0);
          }
        }
      }
    }
    __syncthreads();  // all compute done; xs dead -> axs may overwrite

    // write scaled ax to LDS (bf16, swizzled) + explicit zero pad complement
#pragma unroll
    for (int i = 0; i < 2; i++) {
#pragma unroll
      for (int j2 = 0; j2 < 4; j2++) {
        int row = wr * 64 + (wc * 2 + i) * 16 + lg * 4 + j2;
        int swz = (row & 3) << 3;
        axs[row * 32 + (l15 ^ swz)] = f2bf(axc[i][j2] * SCALE);
        axs[row * 32 + ((l15 + 16) ^ swz)] = 0;
      }
    }
    __syncthreads();

    // lora up-proj: one K=32 MFMA per fragment (B pre-padded), + bias, store
    int kf2 = lg * 8;
    s16x8 blf[4];
#pragma unroll
    for (int n = 0; n < 4; n++) {   // direct global B-frags (L2-hit)
      int colg = cb * BN + wc * 64 + n * 16 + l15;
      blf[n] = *(const s16x8*)(Bbp + ((size_t)(task * D_OUTV) + colg) * 32 + kf2);
    }
    s16x8 axf[4];
#pragma unroll
    for (int m = 0; m < 4; m++) {
      int row = wr * 64 + m * 16 + l15;
      axf[m] = *(const s16x8*)&axs[row * 32 + (kf2 ^ ((row & 3) << 3))];
    }
#pragma unroll
    for (int n = 0; n < 4; n++) {
      int colg = cb * BN + wc * 64 + n * 16 + l15;
      float bv = bias[colg];
#pragma unroll
      for (int m = 0; m < 4; m++) {
        f32x4 r = __builtin_amdgcn_mfma_f32_16x16x32_bf16(axf[m], blf[n], acc[m][n], 0, 0, 0);
#pragma unroll
        for (int j2 = 0; j2 < 4; j2++) {
          int lrow = wr * 64 + m * 16 + lg * 4 + j2;
          if (base + lrow < count) {
            int grow = rowid_l[lrow];
            out[(size_t)grow * D_OUTV + colg] = r[j2] + bv;
          }
        }
      }
    }
  }
}

extern "C" void kernel_launch(void* const* d_in, const int* in_sizes, int n_in,
                              void* d_out, int out_size, void* d_ws, size_t ws_size,
                              hipStream_t stream) {
  const float* x     = (const float*)d_in[0];
  const int*   tasks = (const int*)d_in[1];
  const float* W     = (const float*)d_in[2];
  const float* bias  = (const float*)d_in[3];
  const float* A     = (const float*)d_in[4];
  const float* B     = (const float*)d_in[5];
  float* out = (float*)d_out;
  char* ws = (char*)d_ws;
  u16* Wb  = (u16*)(ws + WB_OFF);
  u16* Ab  = (u16*)(ws + AB_OFF);
  u16* Bbp = (u16*)(ws + BB_OFF);
  int* cnt  = (int*)(ws + CNT_OFF);
  int* ridx = (int*)(ws + RIDX_OFF);
  u16* xg   = (u16*)(ws + XG_OFF);

  hipMemsetAsync(cnt, 0, 512, stream);
  k_convert<<<2560, 256, 0, stream>>>(W, A, B, Wb, Ab, Bbp);
  k_hist<<<NROWS / 256, 256, 0, stream>>>(tasks, cnt);
  k_scan<<<1, 64, 0, stream>>>(cnt);
  k_scatter<<<NROWS / 256, 256, 0, stream>>>(tasks, cnt, ridx);
  k_gatherx<<<NROWS * D_IN / 8 / 256, 256, 0, stream>>>(x, ridx, xg);
  k_main_c<<<NWG, NTHR, 0, stream>>>(xg, bias, Wb, Ab, Bbp, cnt, ridx, out);
}

// Round 11
// 172.558 us; speedup vs baseline: 7.8219x; 1.3651x over previous
//
#include <hip/hip_runtime.h>

// MultiAdapterLinear: out = x @ W^T + b + 2.0 * (B[t] @ (A[t] @ x)) per-row task t
// Strategy: bucket rows by task; pre-gather x into bucket order as bf16;
// fused 128x128 bf16-MFMA GEMM (256 thr, 50.5KB LDS -> 3 WG/CU, SLOTS=3,
// launch_bounds(256,3) -- R10 showed (256,4) starves the unified reg file),
// L2-footprint-aware XCD decode, LoRA balanced across all 4 waves via
// wave-uniform branch with COMPILE-TIME fragment indices (rule #20).

#define D_IN   1024
#define D_OUTV 1024
#define NTASK  32
#define NROWS  32768
#define RLORA  16
#define SCALE  2.0f

typedef unsigned short u16;
typedef __attribute__((ext_vector_type(4))) unsigned short u16x4;
typedef __attribute__((ext_vector_type(8))) unsigned short u16x8;
typedef __attribute__((ext_vector_type(8))) short s16x8;
typedef __attribute__((ext_vector_type(4))) float f32x4;

// workspace layout (bytes)
#define WB_OFF   (0)
#define AB_OFF   (2*1024*1024)
#define BB_OFF   (3*1024*1024)
#define CNT_OFF  (4*1024*1024)
#define RIDX_OFF (CNT_OFF + 512)
#define XG_OFF   (8ull*1024*1024)

__device__ __forceinline__ u16 f2bf(float f) {
  union { float f; unsigned u; } v; v.f = f;
  unsigned r = v.u + 0x7fffu + ((v.u >> 16) & 1u);
  return (u16)(r >> 16);
}

__device__ __forceinline__ void gl2lds16(const void* g, void* s) {
  __builtin_amdgcn_global_load_lds(
      (const __attribute__((address_space(1))) unsigned*)g,
      (__attribute__((address_space(3))) unsigned*)s, 16, 0, 0);
}

__global__ void k_convert(const float* __restrict__ W, const float* __restrict__ A,
                          const float* __restrict__ B, u16* __restrict__ Wb,
                          u16* __restrict__ Ab, u16* __restrict__ Bb) {
  int g = blockIdx.x * blockDim.x + threadIdx.x;
  const int NW = D_OUTV * D_IN / 4;
  const int NA = NTASK * RLORA * D_IN / 4;
  const float* src; u16* dst; int idx;
  if (g < NW) { src = W; dst = Wb; idx = g; }
  else if (g < NW + NA) { src = A; dst = Ab; idx = g - NW; }
  else { src = B; dst = Bb; idx = g - NW - NA; }
  f32x4 v = *(const f32x4*)(src + (size_t)idx * 4);
  u16x4 o;
  o[0] = f2bf(v[0]); o[1] = f2bf(v[1]); o[2] = f2bf(v[2]); o[3] = f2bf(v[3]);
  *(u16x4*)(dst + (size_t)idx * 4) = o;
}

__global__ void k_hist(const int* __restrict__ tasks, int* __restrict__ cnt) {
  __shared__ int h[NTASK];
  int tid = threadIdx.x;
  if (tid < NTASK) h[tid] = 0;
  __syncthreads();
  atomicAdd(&h[tasks[blockIdx.x * 256 + tid]], 1);
  __syncthreads();
  if (tid < NTASK) atomicAdd(&cnt[tid], h[tid]);
}

__global__ void k_scan(int* __restrict__ cnt) {
  int t = threadIdx.x;
  int c = (t < NTASK) ? cnt[t] : 0;
  int v = c;
  for (int d = 1; d < NTASK; d <<= 1) {
    int u = __shfl_up(v, d, 64);
    if (t >= d) v += u;
  }
  if (t < NTASK) {
    int ex = v - c;
    cnt[64 + t] = ex;
    cnt[32 + t] = ex;
    if (t == NTASK - 1) cnt[64 + NTASK] = v;
  }
}

__global__ void k_scatter(const int* __restrict__ tasks, int* __restrict__ cnt,
                          int* __restrict__ ridx) {
  __shared__ int h[NTASK], basev[NTASK];
  int tid = threadIdx.x;
  int b = blockIdx.x * 256 + tid;
  int t = tasks[b];
  if (tid < NTASK) h[tid] = 0;
  __syncthreads();
  atomicAdd(&h[t], 1);
  __syncthreads();
  if (tid < NTASK) {
    basev[tid] = atomicAdd(&cnt[32 + tid], h[tid]);
    h[tid] = 0;
  }
  __syncthreads();
  int r = atomicAdd(&h[t], 1);
  ridx[basev[t] + r] = b;
}

__global__ void k_gatherx(const float* __restrict__ x, const int* __restrict__ ridx,
                          u16* __restrict__ xg) {
  int g = blockIdx.x * 256 + threadIdx.x;
  int pos = g >> 7;
  int c8  = (g & 127) << 3;
  int src = ridx[pos];
  f32x4 a = *(const f32x4*)(x + (size_t)src * D_IN + c8);
  f32x4 b = *(const f32x4*)(x + (size_t)src * D_IN + c8 + 4);
  u16x8 o;
  o[0] = f2bf(a[0]); o[1] = f2bf(a[1]); o[2] = f2bf(a[2]); o[3] = f2bf(a[3]);
  o[4] = f2bf(b[0]); o[5] = f2bf(b[1]); o[6] = f2bf(b[2]); o[7] = f2bf(b[3]);
  *(u16x8*)(xg + (size_t)pos * D_IN + c8) = o;
}

// ---------------- main fused GEMM ----------------
#define BM 128
#define BN 128
#define BK 64
#define NTHR 256
#define SLOTS 3
#define NWG (8 * NTASK * SLOTS)   // 768 WGs = 3 per CU

__global__ __launch_bounds__(NTHR, 3) void k_main_c(
    const u16* __restrict__ xg, const float* __restrict__ bias,
    const u16* __restrict__ Wb, const u16* __restrict__ Ab, const u16* __restrict__ Bb,
    const int* __restrict__ cnt, const int* __restrict__ ridx,
    float* __restrict__ out) {
  __shared__ __align__(16) u16 xs[BM * BK];    // 16 KB
  __shared__ __align__(16) u16 wls[BN * BK];   // 16 KB
  __shared__ u16 als[RLORA * BK];              // 2 KB
  __shared__ u16 axs[BM * 32];                 // 8 KB (rank padded 16->32)
  __shared__ u16 bls[BN * 32];                 // 8 KB (rank padded)
  __shared__ int rowid_l[BM];                  // 0.5 KB  -> ~50.5 KB total

  const int tid = threadIdx.x;
  const int l   = tid & 63;
  const int w   = tid >> 6;          // 0..3
  const int wr  = w >> 1;            // 0..1 : 64-row slice
  const int wc  = w & 1;             // 0..1 : 64-col slice
  const int l15 = l & 15;
  const int lg  = l >> 4;

  // L2-footprint-aware decode: flat&7 = XCD; cb innermost so the 8 adjacent
  // WGs on an XCD share one 256KB xg chunk and cover the whole 2MB W.
  const int flat = blockIdx.x;
  const int xcd  = flat & 7;
  const int j    = flat >> 3;                 // 0..95
  const int cb   = j & 7;                     // colblock 0..7 (inner)
  const int g    = j >> 3;                    // 0..11
  const int task = xcd + 8 * (g & 3);
  const int slot = g >> 2;                    // 0..2

  const int o0    = cnt[64 + task];
  const int count = cnt[64 + task + 1] - o0;

  // stage B[t] col-slice once, zero-padded to 32 on rank dim, swizzled
  for (int s = tid; s < 512; s += NTHR) {
    int c = s >> 2, part = s & 3;
    u16x8 v = {0, 0, 0, 0, 0, 0, 0, 0};
    if (part < 2)
      v = *(const u16x8*)(Bb + ((size_t)(task * D_OUTV) + cb * BN + c) * RLORA + part * 8);
    *(u16x8*)&bls[c * 32 + ((part * 8) ^ ((c & 3) << 3))] = v;
  }
  // zero axs fully once (pad slots stay zero; real slots rewritten per chunk)
  for (int i = tid; i < BM * 32 / 8; i += NTHR) {
    u16x8 z = {0, 0, 0, 0, 0, 0, 0, 0};
    *(u16x8*)&axs[i * 8] = z;
  }

  for (int chunk = slot; chunk * BM < count; chunk += SLOTS) {
    const int base = chunk * BM;
    __syncthreads();  // protect rowid_l/axs from previous chunk's readers
    if (tid < BM) {
      int s = base + tid;
      rowid_l[tid] = (s < count) ? ridx[o0 + s] : 0;
    }

    f32x4 acc[4][4];
    f32x4 axc0, axc1;
    const f32x4 z4 = {0.f, 0.f, 0.f, 0.f};
    axc0 = z4; axc1 = z4;
#pragma unroll
    for (int m = 0; m < 4; m++)
#pragma unroll
      for (int n = 0; n < 4; n++) acc[m][n] = z4;

    for (int kk = 0; kk < D_IN; kk += BK) {
      __syncthreads();  // previous compute done before overwriting tiles
      // x tile: contiguous bucketed bf16 rows; source chunk pre-swizzled
#pragma unroll
      for (int i = 0; i < 4; i++) {
        int ch = i * NTHR + tid;          // 0..1023
        int r = ch >> 3, c = ch & 7;
        int gr = o0 + base + r;
        if (gr > NROWS - 1) gr = NROWS - 1;   // tail clamp (masked at store)
        gl2lds16(xg + (size_t)gr * D_IN + kk + ((c ^ (r & 7)) << 3), &xs[ch * 8]);
      }
      // W tile
#pragma unroll
      for (int i = 0; i < 4; i++) {
        int ch = i * NTHR + tid;
        int wrow = ch >> 3, c = ch & 7;
        gl2lds16(Wb + (size_t)(cb * BN + wrow) * D_IN + kk + ((c ^ (wrow & 7)) << 3),
                 &wls[ch * 8]);
      }
      // A[t] tile
      if (tid < 128) {
        int r = tid >> 3, c = tid & 7;
        gl2lds16(Ab + (size_t)(task * RLORA + r) * D_IN + kk + ((c ^ (r & 7)) << 3),
                 &als[tid * 8]);
      }
      __syncthreads();  // drains vmcnt (global_load_lds) + lgkm

#pragma unroll
      for (int k0 = 0; k0 < BK; k0 += 32) {
        int kf = k0 + lg * 8;
        s16x8 xf[4], wf[4];
#pragma unroll
        for (int m = 0; m < 4; m++) {
          int row = wr * 64 + m * 16 + l15;
          xf[m] = *(const s16x8*)&xs[row * BK + (kf ^ ((row & 7) << 3))];
        }
#pragma unroll
        for (int n = 0; n < 4; n++) {
          int col = wc * 64 + n * 16 + l15;
          wf[n] = *(const s16x8*)&wls[col * BK + (kf ^ ((col & 7) << 3))];
        }
#pragma unroll
        for (int m = 0; m < 4; m++)
#pragma unroll
          for (int n = 0; n < 4; n++)
            acc[m][n] = __builtin_amdgcn_mfma_f32_16x16x32_bf16(xf[m], wf[n], acc[m][n], 0, 0, 0);
        // LoRA down-proj, balanced across waves: wave (wr,wc) owns m-frags
        // {2wc, 2wc+1}; wave-uniform branch, compile-time indices (rule #20)
        {
          s16x8 af = *(const s16x8*)&als[l15 * BK + (kf ^ ((l15 & 7) << 3))];
          if (wc == 0) {
            axc0 = __builtin_amdgcn_mfma_f32_16x16x32_bf16(xf[0], af, axc0, 0, 0, 0);
            axc1 = __builtin_amdgcn_mfma_f32_16x16x32_bf16(xf[1], af, axc1, 0, 0, 0);
          } else {
            axc0 = __builtin_amdgcn_mfma_f32_16x16x32_bf16(xf[2], af, axc0, 0, 0, 0);
            axc1 = __builtin_amdgcn_mfma_f32_16x16x32_bf16(xf[3], af, axc1, 0, 0, 0);
          }
        }
      }
    }
    __syncthreads();  // all compute done

    // write scaled ax to LDS (bf16, swizzled; pad region untouched zeros)
    // wave (wr,wc) wrote m-frags {2wc, 2wc+1} -> rows wr*64 + (2wc+i)*16 + ...
#pragma unroll
    for (int i = 0; i < 2; i++) {
#pragma unroll
      for (int j2 = 0; j2 < 4; j2++) {
        int row = wr * 64 + (wc * 2 + i) * 16 + lg * 4 + j2;
        float v = (i == 0) ? axc0[j2] : axc1[j2];
        axs[row * 32 + (l15 ^ ((row & 3) << 3))] = f2bf(v * SCALE);
      }
    }
    __syncthreads();

    // lora up-proj: one K=32 (zero-padded) MFMA per fragment, + bias, store
    int kf2 = lg * 8;
    s16x8 axf[4], blf[4];
#pragma unroll
    for (int m = 0; m < 4; m++) {
      int row = wr * 64 + m * 16 + l15;
      axf[m] = *(const s16x8*)&axs[row * 32 + (kf2 ^ ((row & 3) << 3))];
    }
#pragma unroll
    for (int n = 0; n < 4; n++) {
      int col = wc * 64 + n * 16 + l15;
      blf[n] = *(const s16x8*)&bls[col * 32 + (kf2 ^ ((col & 3) << 3))];
    }
#pragma unroll
    for (int n = 0; n < 4; n++) {
      int colg = cb * BN + wc * 64 + n * 16 + l15;
      float bv = bias[colg];
#pragma unroll
      for (int m = 0; m < 4; m++) {
        f32x4 r = __builtin_amdgcn_mfma_f32_16x16x32_bf16(axf[m], blf[n], acc[m][n], 0, 0, 0);
#pragma unroll
        for (int j2 = 0; j2 < 4; j2++) {
          int lrow = wr * 64 + m * 16 + lg * 4 + j2;
          if (base + lrow < count) {
            int grow = rowid_l[lrow];
            out[(size_t)grow * D_OUTV + colg] = r[j2] + bv;
          }
        }
      }
    }
  }
}

extern "C" void kernel_launch(void* const* d_in, const int* in_sizes, int n_in,
                              void* d_out, int out_size, void* d_ws, size_t ws_size,
                              hipStream_t stream) {
  const float* x     = (const float*)d_in[0];
  const int*   tasks = (const int*)d_in[1];
  const float* W     = (const float*)d_in[2];
  const float* bias  = (const float*)d_in[3];
  const float* A     = (const float*)d_in[4];
  const float* B     = (const float*)d_in[5];
  float* out = (float*)d_out;
  char* ws = (char*)d_ws;
  u16* Wb = (u16*)(ws + WB_OFF);
  u16* Ab = (u16*)(ws + AB_OFF);
  u16* Bb = (u16*)(ws + BB_OFF);
  int* cnt  = (int*)(ws + CNT_OFF);
  int* ridx = (int*)(ws + RIDX_OFF);
  u16* xg   = (u16*)(ws + XG_OFF);

  hipMemsetAsync(cnt, 0, 512, stream);
  k_convert<<<2048, 256, 0, stream>>>(W, A, B, Wb, Ab, Bb);
  k_hist<<<NROWS / 256, 256, 0, stream>>>(tasks, cnt);
  k_scan<<<1, 64, 0, stream>>>(cnt);
  k_scatter<<<NROWS / 256, 256, 0, stream>>>(tasks, cnt, ridx);
  k_gatherx<<<NROWS * D_IN / 8 / 256, 256, 0, stream>>>(x, ridx, xg);
  k_main_c<<<NWG, NTHR, 0, stream>>>(xg, bias, Wb, Ab, Bb, cnt, ridx, out);
}